// Round 12
// baseline (160.211 us; speedup 1.0000x reference)
//
#include <hip/hip_runtime.h>
#include <math.h>

#define EMBED 1024
#define NH 16
#define NKV 4
#define HD 64
#define SN 1024
#define LP 4096
#define WIN 32

// log2(10000)/32
#define FREQ_C 0.4152410118609203f

typedef float floatx4 __attribute__((ext_vector_type(4)));
typedef __bf16 bf16x8 __attribute__((ext_vector_type(8)));

// ---------------------------------------------------------------------------
// Prep: hidden -> bf16 row-major; weights -> bf16 [n][k] (transposed).
// grid 896: jb<256 wq tiles, <320 wk, <384 wv, <640 wo, >=640 hidden convert.
// ---------------------------------------------------------------------------
__global__ __launch_bounds__(256) void prep_kernel(
    const float* __restrict__ hidden, const float* __restrict__ wq,
    const float* __restrict__ wk, const float* __restrict__ wv,
    const float* __restrict__ wo,
    __bf16* __restrict__ hidb, __bf16* __restrict__ wqT,
    __bf16* __restrict__ wkT, __bf16* __restrict__ wvT,
    __bf16* __restrict__ woT)
{
    const int jb = blockIdx.x, tid = threadIdx.x;
    if (jb >= 640) {
        const size_t base = (size_t)(jb - 640) * 4096 + (size_t)tid * 16;
        float4 f0 = *(const float4*)(hidden + base);
        float4 f1 = *(const float4*)(hidden + base + 4);
        float4 f2 = *(const float4*)(hidden + base + 8);
        float4 f3 = *(const float4*)(hidden + base + 12);
        bf16x8 o0, o1;
        o0[0] = (__bf16)f0.x; o0[1] = (__bf16)f0.y;
        o0[2] = (__bf16)f0.z; o0[3] = (__bf16)f0.w;
        o0[4] = (__bf16)f1.x; o0[5] = (__bf16)f1.y;
        o0[6] = (__bf16)f1.z; o0[7] = (__bf16)f1.w;
        o1[0] = (__bf16)f2.x; o1[1] = (__bf16)f2.y;
        o1[2] = (__bf16)f2.z; o1[3] = (__bf16)f2.w;
        o1[4] = (__bf16)f3.x; o1[5] = (__bf16)f3.y;
        o1[6] = (__bf16)f3.z; o1[7] = (__bf16)f3.w;
        *(bf16x8*)(hidb + base) = o0;
        *(bf16x8*)(hidb + base + 8) = o1;
        return;
    }
    const float* src; __bf16* dst; int N, tk, tn;
    if (jb < 256)      { src = wq; dst = wqT; N = 1024; tk = jb >> 4;         tn = jb & 15; }
    else if (jb < 320) { src = wk; dst = wkT; N = 256;  tk = (jb - 256) >> 2; tn = (jb - 256) & 3; }
    else if (jb < 384) { src = wv; dst = wvT; N = 256;  tk = (jb - 320) >> 2; tn = (jb - 320) & 3; }
    else               { src = wo; dst = woT; N = 1024; tk = (jb - 384) >> 4; tn = (jb - 384) & 15; }

    __shared__ float T[64][65];
    {
        const int r = tid >> 2, c0 = (tid & 3) * 16;
        const float* sp = src + (size_t)(tk * 64 + r) * N + tn * 64 + c0;
        float4 v0 = *(const float4*)(sp + 0);
        float4 v1 = *(const float4*)(sp + 4);
        float4 v2 = *(const float4*)(sp + 8);
        float4 v3 = *(const float4*)(sp + 12);
        *(float4*)&T[r][c0 + 0] = v0;
        *(float4*)&T[r][c0 + 4] = v1;
        *(float4*)&T[r][c0 + 8] = v2;
        *(float4*)&T[r][c0 + 12] = v3;
    }
    __syncthreads();
    {
        const int n = tid >> 2, k0 = (tid & 3) * 16;
        bf16x8 o0, o1;
#pragma unroll
        for (int j = 0; j < 8; j++) {
            o0[j] = (__bf16)T[k0 + j][n];
            o1[j] = (__bf16)T[k0 + 8 + j][n];
        }
        __bf16* dp = dst + (size_t)(tn * 64 + n) * 1024 + tk * 64 + k0;
        *(bf16x8*)dp = o0;
        *(bf16x8*)(dp + 8) = o1;
    }
}

// ---------------------------------------------------------------------------
// MFMA QKV GEMM + fused RoPE, 32x64 tiles (R9 winner). grid (24,32).
// ---------------------------------------------------------------------------
__global__ __launch_bounds__(256) void qkv_mfma_kernel(
    const __bf16* __restrict__ hidb, const __bf16* __restrict__ wqT,
    const __bf16* __restrict__ wkT, const __bf16* __restrict__ wvT,
    const int* __restrict__ new_t, const int* __restrict__ new_d,
    const int* __restrict__ new_b,
    __bf16* __restrict__ qws, float* __restrict__ knp, float* __restrict__ vnp)
{
    __shared__ __bf16 ASh[32][72];
    __shared__ __bf16 BSh[64][72];

    const int tid = threadIdx.x;
    const int lane = tid & 63, w = tid >> 6;
    const int g = lane >> 4, c = lane & 15;
    const int bx = blockIdx.x, by = blockIdx.y;

    int mode, cbase;
    const __bf16* W;
    if (bx < 16)      { mode = 0; W = wqT; cbase = bx * 64; }
    else if (bx < 20) { mode = 1; W = wkT; cbase = (bx - 16) * 64; }
    else              { mode = 2; W = wvT; cbase = (bx - 20) * 64; }

    const int arow = tid >> 3, ak = (tid & 7) * 8;
    const __bf16* Ap = hidb + (size_t)(by * 32 + arow) * EMBED + ak;
    const int bn = tid & 63, bk0 = (tid >> 6) * 16;
    const __bf16* Bp = W + (size_t)(cbase + bn) * 1024 + bk0;

    floatx4 acc[2] = {floatx4(0.f), floatx4(0.f)};

    bf16x8 a0 = *(const bf16x8*)(Ap);
    bf16x8 b0 = *(const bf16x8*)(Bp);
    bf16x8 b1 = *(const bf16x8*)(Bp + 8);

    const int mt = (w & 1) * 16;
    const int nt0 = (w >> 1) * 2;

    for (int k0 = 0; k0 < EMBED; k0 += 64) {
        __syncthreads();
        *(bf16x8*)&ASh[arow][ak] = a0;
        *(bf16x8*)&BSh[bn][bk0] = b0;
        *(bf16x8*)&BSh[bn][bk0 + 8] = b1;
        __syncthreads();
        if (k0 + 64 < EMBED) {
            a0 = *(const bf16x8*)(Ap + k0 + 64);
            b0 = *(const bf16x8*)(Bp + k0 + 64);
            b1 = *(const bf16x8*)(Bp + k0 + 72);
        }
        bf16x8 af0 = *(const bf16x8*)&ASh[mt + c][g * 8];
        bf16x8 af1 = *(const bf16x8*)&ASh[mt + c][32 + g * 8];
#pragma unroll
        for (int t = 0; t < 2; t++) {
            const int tn = nt0 + t;
            bf16x8 bf0 = *(const bf16x8*)&BSh[tn * 16 + c][g * 8];
            bf16x8 bf1 = *(const bf16x8*)&BSh[tn * 16 + c][32 + g * 8];
            acc[t] = __builtin_amdgcn_mfma_f32_16x16x32_bf16(af0, bf0, acc[t], 0, 0, 0);
            acc[t] = __builtin_amdgcn_mfma_f32_16x16x32_bf16(af1, bf1, acc[t], 0, 0, 0);
        }
    }

    const int m0 = mt + g * 4;
    if (mode == 2) {
        const int kvh = bx - 20;
#pragma unroll
        for (int r = 0; r < 4; r++) {
            const int token = by * 32 + m0 + r;
#pragma unroll
            for (int t = 0; t < 2; t++)
                vnp[((size_t)kvh * SN + token) * HD + (nt0 + t) * 16 + c] = acc[t][r];
        }
    } else {
        float fr[2];
#pragma unroll
        for (int t = 0; t < 2; t++) {
            const int d = (cbase + (nt0 + t) * 16 + c) & 63;
            fr[t] = exp2f(-FREQ_C * (float)(d >> 1));
        }
        const int par = c & 1;
#pragma unroll
        for (int r = 0; r < 4; r++) {
            const int token = by * 32 + m0 + r;
            const float ft = (float)new_t[token];
            const float fdb = (float)(new_d[token] + new_b[token]);
#pragma unroll
            for (int t = 0; t < 2; t++) {
                const float ang = ft * fr[t] + fdb * (fr[t] * 100.0f);
                float sv, cv;
                sincosf(ang, &sv, &cv);
                const float x = acc[t][r];
                const float xp = __shfl_xor(x, 1, 64);
                const float y = par ? (xp * sv + x * cv) : (x * cv - xp * sv);
                const int col = cbase + (nt0 + t) * 16 + c;
                if (mode == 0) {
                    qws[(size_t)token * EMBED + col] = (__bf16)y;
                } else {
                    const int kvh = bx - 16;
                    knp[((size_t)kvh * SN + token) * HD + (col & 63)] = y;
                }
            }
        }
    }
}

// ---------------------------------------------------------------------------
// MFMA output projection, 32x64 tiles (R9 winner). grid (16,32).
// ---------------------------------------------------------------------------
__global__ __launch_bounds__(256) void out_mfma_kernel(
    const __bf16* __restrict__ ctxb, const __bf16* __restrict__ woT,
    float* __restrict__ C)
{
    __shared__ __bf16 ASh[32][72];
    __shared__ __bf16 BSh[64][72];

    const int tid = threadIdx.x;
    const int lane = tid & 63, w = tid >> 6;
    const int g = lane >> 4, c = lane & 15;
    const int bx = blockIdx.x, by = blockIdx.y;

    const int arow = tid >> 3, ak = (tid & 7) * 8;
    const __bf16* Ap = ctxb + (size_t)(by * 32 + arow) * EMBED + ak;
    const int bn = tid & 63, bk0 = (tid >> 6) * 16;
    const __bf16* Bp = woT + (size_t)(bx * 64 + bn) * 1024 + bk0;

    floatx4 acc[2] = {floatx4(0.f), floatx4(0.f)};

    bf16x8 a0 = *(const bf16x8*)(Ap);
    bf16x8 b0 = *(const bf16x8*)(Bp);
    bf16x8 b1 = *(const bf16x8*)(Bp + 8);

    const int mt = (w & 1) * 16;
    const int nt0 = (w >> 1) * 2;

    for (int k0 = 0; k0 < EMBED; k0 += 64) {
        __syncthreads();
        *(bf16x8*)&ASh[arow][ak] = a0;
        *(bf16x8*)&BSh[bn][bk0] = b0;
        *(bf16x8*)&BSh[bn][bk0 + 8] = b1;
        __syncthreads();
        if (k0 + 64 < EMBED) {
            a0 = *(const bf16x8*)(Ap + k0 + 64);
            b0 = *(const bf16x8*)(Bp + k0 + 64);
            b1 = *(const bf16x8*)(Bp + k0 + 72);
        }
        bf16x8 af0 = *(const bf16x8*)&ASh[mt + c][g * 8];
        bf16x8 af1 = *(const bf16x8*)&ASh[mt + c][32 + g * 8];
#pragma unroll
        for (int t = 0; t < 2; t++) {
            const int tn = nt0 + t;
            bf16x8 bf0 = *(const bf16x8*)&BSh[tn * 16 + c][g * 8];
            bf16x8 bf1 = *(const bf16x8*)&BSh[tn * 16 + c][32 + g * 8];
            acc[t] = __builtin_amdgcn_mfma_f32_16x16x32_bf16(af0, bf0, acc[t], 0, 0, 0);
            acc[t] = __builtin_amdgcn_mfma_f32_16x16x32_bf16(af1, bf1, acc[t], 0, 0, 0);
        }
    }

    const int m0 = mt + g * 4;
#pragma unroll
    for (int r = 0; r < 4; r++) {
        const int row = by * 32 + m0 + r;
#pragma unroll
        for (int t = 0; t < 2; t++)
            C[(size_t)row * EMBED + bx * 64 + (nt0 + t) * 16 + c] = acc[t][r];
    }
}

// ---------------------------------------------------------------------------
// MFMA flash attention, GQA-fused (R10 winner) with occupancy fixes:
// (1) prefetch converts/packs KV to bf16 in-registers (17 regs vs 33;
//     staging section = pure LDS stores);
// (2) kt-outer S-phase: each K fragment read once from LDS, used by all 4
//     q-tiles; exp is elementwise (fixed-shift softmax) so no row state;
// (3) PS stride 66 -> LDS 51.25 KB; __launch_bounds__(256,3) -> 3 blocks/CU.
// grid 512 = 16 f x 4 kvh x 8 split, 256 threads = 4 waves (wave = head).
// ---------------------------------------------------------------------------
#define PREFETCH_CHUNK(CI)                                                     \
    {                                                                          \
        const int base_ = (myStart + (CI)) << 6;                               \
        const int gk_ = base_ + skk;                                           \
        if (gk_ < Nk) {                                                        \
            const float* kp_ = (gk_ < nPast)                                   \
                ? past_k + ((size_t)(kvh * LP + p0 + gk_)) * HD + sd0          \
                : knp + ((size_t)(kvh * SN + (gk_ - nPast))) * HD + sd0;       \
            float4 k0_ = *(const float4*)(kp_ + 0);                            \
            float4 k1_ = *(const float4*)(kp_ + 4);                            \
            float4 k2_ = *(const float4*)(kp_ + 8);                            \
            float4 k3_ = *(const float4*)(kp_ + 12);                           \
            kbA[0] = (__bf16)k0_.x; kbA[1] = (__bf16)k0_.y;                    \
            kbA[2] = (__bf16)k0_.z; kbA[3] = (__bf16)k0_.w;                    \
            kbA[4] = (__bf16)k1_.x; kbA[5] = (__bf16)k1_.y;                    \
            kbA[6] = (__bf16)k1_.z; kbA[7] = (__bf16)k1_.w;                    \
            kbB[0] = (__bf16)k2_.x; kbB[1] = (__bf16)k2_.y;                    \
            kbB[2] = (__bf16)k2_.z; kbB[3] = (__bf16)k2_.w;                    \
            kbB[4] = (__bf16)k3_.x; kbB[5] = (__bf16)k3_.y;                    \
            kbB[6] = (__bf16)k3_.z; kbB[7] = (__bf16)k3_.w;                    \
        } else {                                                               \
            kbA = (bf16x8)(__bf16)0.f; kbB = kbA;                              \
        }                                                                      \
        float e0_[8] = {0,0,0,0,0,0,0,0}, e1_[8] = {0,0,0,0,0,0,0,0};          \
        {                                                                      \
            const int gv0_ = base_ + 2 * kp2;                                  \
            if (gv0_ < Nk) {                                                   \
                const float* vp_ = (gv0_ < nPast)                              \
                    ? past_v + ((size_t)(kvh * LP + p0 + gv0_)) * HD + vdb     \
                    : vnp + ((size_t)(kvh * SN + (gv0_ - nPast))) * HD + vdb;  \
                *(float4*)&e0_[0] = *(const float4*)(vp_ + 0);                 \
                *(float4*)&e0_[4] = *(const float4*)(vp_ + 4);                 \
            }                                                                  \
            const int gv1_ = gv0_ + 1;                                         \
            if (gv1_ < Nk) {                                                   \
                const float* vp_ = (gv1_ < nPast)                              \
                    ? past_v + ((size_t)(kvh * LP + p0 + gv1_)) * HD + vdb     \
                    : vnp + ((size_t)(kvh * SN + (gv1_ - nPast))) * HD + vdb;  \
                *(float4*)&e1_[0] = *(const float4*)(vp_ + 0);                 \
                *(float4*)&e1_[4] = *(const float4*)(vp_ + 4);                 \
            }                                                                  \
        }                                                                      \
        _Pragma("unroll")                                                      \
        for (int j_ = 0; j_ < 8; j_++) {                                       \
            union { __bf16 b[2]; unsigned u; } pk_;                            \
            pk_.b[0] = (__bf16)e0_[j_];                                        \
            pk_.b[1] = (__bf16)e1_[j_];                                        \
            vpk[j_] = pk_.u;                                                   \
        }                                                                      \
        if (tid < 64) ptreg = (base_ + tid < Nk)                               \
            ? ((base_ + tid < nPast) ? past_t[p0 + base_ + tid]                \
                                     : new_t[base_ + tid - nPast])             \
            : 0x7fffffff;                                                      \
    }

__global__ __launch_bounds__(256, 3) void attn_kernel(
    const __bf16* __restrict__ qws, const float* __restrict__ past_k,
    const float* __restrict__ past_v, const float* __restrict__ knp,
    const float* __restrict__ vnp, const int* __restrict__ new_t,
    const int* __restrict__ past_t, float* __restrict__ opart,
    float* __restrict__ lpart)
{
    __shared__ __bf16 KS[64][72];      // K  [key][d] (shared by 4 heads)
    __shared__ __bf16 VS[64][72];      // V^T [d][key]
    __shared__ __bf16 PS[4][64][66];   // per-wave P [q][key], stride 66
    __shared__ float MSK[64];

    const int tid = threadIdx.x;
    const int i = blockIdx.x;
    const int kvh = i & 3;
    const int sidx = (i >> 2) & 7;
    const int f = i >> 5;

    const int lane = tid & 63, w = tid >> 6;
    const int g = lane >> 4, c = lane & 15;
    const int h = kvh * 4 + w;   // wave w owns head h

    const int tmax = new_t[SN - 1];
    const int min_time = tmax - (WIN - 1);
    const int qtf = new_t[f * 64];

    int lo = 0, hi = LP;
    while (lo < hi) {
        int mid = (lo + hi) >> 1;
        if (past_t[mid] >= min_time) hi = mid; else lo = mid + 1;
    }
    const int p0 = lo;
    const int nPast = LP - p0;
    const int Nk = nPast + (f + 1) * 64;

    const int nch = (Nk + 63) >> 6;
    const int qch = nch >> 3, rem = nch & 7;
    const int myCount = qch + (sidx < rem ? 1 : 0);
    const int myStart = sidx * qch + (sidx < rem ? sidx : rem);

    // ---- Q fragments: 4 q-tiles x 2 K-steps for head h ----
    bf16x8 aQ[4][2];
#pragma unroll
    for (int qt = 0; qt < 4; qt++) {
        const __bf16* qp = qws + (size_t)(f * 64 + qt * 16 + c) * EMBED + h * HD + g * 8;
        aQ[qt][0] = *(const bf16x8*)(qp);
        aQ[qt][1] = *(const bf16x8*)(qp + 32);
    }

    floatx4 oacc[4][4];
#pragma unroll
    for (int qt = 0; qt < 4; qt++)
#pragma unroll
        for (int t = 0; t < 4; t++) oacc[qt][t] = floatx4(0.f);
    floatx4 lacc[4] = {floatx4(0.f), floatx4(0.f), floatx4(0.f), floatx4(0.f)};
    bf16x8 bOnes;
#pragma unroll
    for (int j = 0; j < 8; j++) bOnes[j] = (__bf16)1.0f;

    const float scale = 0.125f;

    const int skk = tid >> 2, sd0 = (tid & 3) * 16;   // K: key, d-block
    const int kp2 = tid & 31, vdb = (tid >> 5) * 8;   // V: key-pair, d-block

    bf16x8 kbA, kbB;
    unsigned vpk[8];
    int ptreg = 0x7fffffff;

    if (myCount > 0) PREFETCH_CHUNK(0);

    for (int chi = 0; chi < myCount; ++chi) {
        __syncthreads();   // prior chunk's KS/VS reads complete

        // ---- pure-store staging (data pre-converted in prefetch) ----
        *(bf16x8*)&KS[skk][sd0] = kbA;
        *(bf16x8*)&KS[skk][sd0 + 8] = kbB;
#pragma unroll
        for (int j = 0; j < 8; j++)
            *(unsigned*)&VS[vdb + j][2 * kp2] = vpk[j];
        if (tid < 64)
            MSK[tid] = (ptreg <= qtf) ? 0.f : -1e30f;
        __syncthreads();

        if (chi + 1 < myCount) PREFETCH_CHUNK(chi + 1);

        // ---- S phase, kt-outer: each K fragment read once, all 4 q-tiles --
#pragma unroll
        for (int kt = 0; kt < 4; kt++) {
            bf16x8 k0 = *(const bf16x8*)&KS[kt * 16 + c][g * 8];
            bf16x8 k1 = *(const bf16x8*)&KS[kt * 16 + c][32 + g * 8];
            const float mk = MSK[kt * 16 + c];
#pragma unroll
            for (int qt = 0; qt < 4; qt++) {
                floatx4 s = floatx4(0.f);
                s = __builtin_amdgcn_mfma_f32_16x16x32_bf16(aQ[qt][0], k0, s, 0, 0, 0);
                s = __builtin_amdgcn_mfma_f32_16x16x32_bf16(aQ[qt][1], k1, s, 0, 0, 0);
#pragma unroll
                for (int r = 0; r < 4; r++)
                    PS[w][qt * 16 + g * 4 + r][kt * 16 + c] =
                        (__bf16)__expf(s[r] * scale + mk);
            }
        }

        // ---- O += P V ; l += P 1 ----
#pragma unroll
        for (int s = 0; s < 2; s++) {
            bf16x8 af[4];
#pragma unroll
            for (int qt = 0; qt < 4; qt++)
                af[qt] = *(const bf16x8*)&PS[w][qt * 16 + c][s * 32 + g * 8];
#pragma unroll
            for (int qt = 0; qt < 4; qt++)
                lacc[qt] = __builtin_amdgcn_mfma_f32_16x16x32_bf16(af[qt], bOnes, lacc[qt], 0, 0, 0);
#pragma unroll
            for (int t = 0; t < 4; t++) {
                bf16x8 vf = *(const bf16x8*)&VS[t * 16 + c][s * 32 + g * 8];
#pragma unroll
                for (int qt = 0; qt < 4; qt++)
                    oacc[qt][t] = __builtin_amdgcn_mfma_f32_16x16x32_bf16(af[qt], vf, oacc[qt][t], 0, 0, 0);
            }
        }
    }

    // ---- partial epilogue: raw O and l for head h ----
    float* Op = opart + ((size_t)(f * 16 + h) * 8 + sidx) * 4096;
    float* lp = lpart + ((size_t)(f * 16 + h) * 8 + sidx) * 64;
#pragma unroll
    for (int qt = 0; qt < 4; qt++) {
#pragma unroll
        for (int r = 0; r < 4; r++) {
            const int q = qt * 16 + g * 4 + r;
#pragma unroll
            for (int t = 0; t < 4; t++)
                Op[(size_t)q * 64 + t * 16 + c] = oacc[qt][t][r];
            if (c == 0) lp[q] = lacc[qt][r];
        }
    }
}

// ---------------------------------------------------------------------------
// Merge 8 split-K partials -> bf16 ctx. grid (16,16), 256 threads.
// ---------------------------------------------------------------------------
__global__ __launch_bounds__(256) void attn_merge_kernel(
    const float* __restrict__ opart, const float* __restrict__ lpart,
    __bf16* __restrict__ ctxb)
{
    const int f = blockIdx.x, h = blockIdx.y;
    const int tid = threadIdx.x;
    const int q = tid >> 2, d0 = (tid & 3) * 16;
    const size_t fh = (size_t)(f * 16 + h);

    float l = 0.f;
#pragma unroll
    for (int s = 0; s < 8; s++) l += lpart[(fh * 8 + s) * 64 + q];
    const float inv = (l > 0.f) ? (1.f / l) : 0.f;

    float o[16] = {};
#pragma unroll
    for (int s = 0; s < 8; s++) {
        const float* Os = opart + (fh * 8 + s) * 4096 + (size_t)q * 64 + d0;
#pragma unroll
        for (int v = 0; v < 4; v++) {
            float4 ov = *(const float4*)(Os + v * 4);
            o[v * 4 + 0] += ov.x;
            o[v * 4 + 1] += ov.y;
            o[v * 4 + 2] += ov.z;
            o[v * 4 + 3] += ov.w;
        }
    }
    bf16x8 o0, o1;
#pragma unroll
    for (int j = 0; j < 8; j++) {
        o0[j] = (__bf16)(o[j] * inv);
        o1[j] = (__bf16)(o[8 + j] * inv);
    }
    __bf16* cp = ctxb + (size_t)(f * 64 + q) * EMBED + h * HD + d0;
    *(bf16x8*)cp = o0;
    *(bf16x8*)(cp + 8) = o1;
}

// ---------------------------------------------------------------------------
extern "C" void kernel_launch(void* const* d_in, const int* in_sizes, int n_in,
                              void* d_out, int out_size, void* d_ws, size_t ws_size,
                              hipStream_t stream) {
    const float* hidden = (const float*)d_in[0];
    const float* past_k = (const float*)d_in[1];
    const float* past_v = (const float*)d_in[2];
    const float* wq     = (const float*)d_in[3];
    const float* wk     = (const float*)d_in[4];
    const float* wv     = (const float*)d_in[5];
    const float* wo     = (const float*)d_in[6];
    const int* new_t    = (const int*)d_in[7];
    const int* new_d    = (const int*)d_in[8];
    const int* new_b    = (const int*)d_in[9];
    const int* past_t   = (const int*)d_in[10];

    float* out = (float*)d_out;                 // (1,1024,1024)
    float* knp = out + SN * EMBED;              // (1,4,1024,64) roped Kn
    float* vnp = knp + NKV * SN * HD;           // (1,4,1024,64) Vn

    // workspace layout (R10):
    float* lpart = (float*)d_ws;                         // 16*16*8*64 floats
    float* opart = lpart + (size_t)16 * 16 * 8 * 64;     // 16*16*8*4096 floats
    __bf16* qws  = (__bf16*)(opart + (size_t)16 * 16 * 8 * 4096);  // 1M bf16
    __bf16* hidb = qws + (size_t)SN * EMBED;             // 1M bf16
    __bf16* wqT  = hidb + (size_t)SN * EMBED;            // 1M bf16
    __bf16* wkT  = wqT + (size_t)1024 * 1024;            // 256K bf16
    __bf16* wvT  = wkT + (size_t)256 * 1024;             // 256K bf16
    __bf16* woT  = wvT + (size_t)256 * 1024;             // 1M bf16
    __bf16* ctxb = woT + (size_t)1024 * 1024;            // 1M bf16

    prep_kernel<<<dim3(896), 256, 0, stream>>>(
        hidden, wq, wk, wv, wo, hidb, wqT, wkT, wvT, woT);
    qkv_mfma_kernel<<<dim3(24, 32), 256, 0, stream>>>(
        hidb, wqT, wkT, wvT, new_t, new_d, new_b, qws, knp, vnp);
    attn_kernel<<<dim3(512), 256, 0, stream>>>(
        qws, past_k, past_v, knp, vnp, new_t, past_t, opart, lpart);
    attn_merge_kernel<<<dim3(16, 16), 256, 0, stream>>>(opart, lpart, ctxb);
    out_mfma_kernel<<<dim3(16, 32), 256, 0, stream>>>(ctxb, woT, out);
}

// Round 13
// 147.240 us; speedup vs baseline: 1.0881x; 1.0881x over previous
//
#include <hip/hip_runtime.h>
#include <math.h>

#define EMBED 1024
#define NH 16
#define NKV 4
#define HD 64
#define SN 1024
#define LP 4096
#define WIN 32

// log2(10000)/32
#define FREQ_C 0.4152410118609203f

typedef float floatx4 __attribute__((ext_vector_type(4)));
typedef __bf16 bf16x8 __attribute__((ext_vector_type(8)));

// ---------------------------------------------------------------------------
// Prep: hidden -> bf16 row-major; weights -> bf16 [n][k] (transposed).
// grid 896: jb<256 wq tiles, <320 wk, <384 wv, <640 wo, >=640 hidden convert.
// ---------------------------------------------------------------------------
__global__ __launch_bounds__(256) void prep_kernel(
    const float* __restrict__ hidden, const float* __restrict__ wq,
    const float* __restrict__ wk, const float* __restrict__ wv,
    const float* __restrict__ wo,
    __bf16* __restrict__ hidb, __bf16* __restrict__ wqT,
    __bf16* __restrict__ wkT, __bf16* __restrict__ wvT,
    __bf16* __restrict__ woT)
{
    const int jb = blockIdx.x, tid = threadIdx.x;
    if (jb >= 640) {
        const size_t base = (size_t)(jb - 640) * 4096 + (size_t)tid * 16;
        float4 f0 = *(const float4*)(hidden + base);
        float4 f1 = *(const float4*)(hidden + base + 4);
        float4 f2 = *(const float4*)(hidden + base + 8);
        float4 f3 = *(const float4*)(hidden + base + 12);
        bf16x8 o0, o1;
        o0[0] = (__bf16)f0.x; o0[1] = (__bf16)f0.y;
        o0[2] = (__bf16)f0.z; o0[3] = (__bf16)f0.w;
        o0[4] = (__bf16)f1.x; o0[5] = (__bf16)f1.y;
        o0[6] = (__bf16)f1.z; o0[7] = (__bf16)f1.w;
        o1[0] = (__bf16)f2.x; o1[1] = (__bf16)f2.y;
        o1[2] = (__bf16)f2.z; o1[3] = (__bf16)f2.w;
        o1[4] = (__bf16)f3.x; o1[5] = (__bf16)f3.y;
        o1[6] = (__bf16)f3.z; o1[7] = (__bf16)f3.w;
        *(bf16x8*)(hidb + base) = o0;
        *(bf16x8*)(hidb + base + 8) = o1;
        return;
    }
    const float* src; __bf16* dst; int N, tk, tn;
    if (jb < 256)      { src = wq; dst = wqT; N = 1024; tk = jb >> 4;         tn = jb & 15; }
    else if (jb < 320) { src = wk; dst = wkT; N = 256;  tk = (jb - 256) >> 2; tn = (jb - 256) & 3; }
    else if (jb < 384) { src = wv; dst = wvT; N = 256;  tk = (jb - 320) >> 2; tn = (jb - 320) & 3; }
    else               { src = wo; dst = woT; N = 1024; tk = (jb - 384) >> 4; tn = (jb - 384) & 15; }

    __shared__ float T[64][65];
    {
        const int r = tid >> 2, c0 = (tid & 3) * 16;
        const float* sp = src + (size_t)(tk * 64 + r) * N + tn * 64 + c0;
        float4 v0 = *(const float4*)(sp + 0);
        float4 v1 = *(const float4*)(sp + 4);
        float4 v2 = *(const float4*)(sp + 8);
        float4 v3 = *(const float4*)(sp + 12);
        *(float4*)&T[r][c0 + 0] = v0;
        *(float4*)&T[r][c0 + 4] = v1;
        *(float4*)&T[r][c0 + 8] = v2;
        *(float4*)&T[r][c0 + 12] = v3;
    }
    __syncthreads();
    {
        const int n = tid >> 2, k0 = (tid & 3) * 16;
        bf16x8 o0, o1;
#pragma unroll
        for (int j = 0; j < 8; j++) {
            o0[j] = (__bf16)T[k0 + j][n];
            o1[j] = (__bf16)T[k0 + 8 + j][n];
        }
        __bf16* dp = dst + (size_t)(tn * 64 + n) * 1024 + tk * 64 + k0;
        *(bf16x8*)dp = o0;
        *(bf16x8*)(dp + 8) = o1;
    }
}

// ---------------------------------------------------------------------------
// MFMA QKV GEMM + fused RoPE, 32x64 tiles. grid (24,32).
// ---------------------------------------------------------------------------
__global__ __launch_bounds__(256) void qkv_mfma_kernel(
    const __bf16* __restrict__ hidb, const __bf16* __restrict__ wqT,
    const __bf16* __restrict__ wkT, const __bf16* __restrict__ wvT,
    const int* __restrict__ new_t, const int* __restrict__ new_d,
    const int* __restrict__ new_b,
    __bf16* __restrict__ qws, float* __restrict__ knp, float* __restrict__ vnp)
{
    __shared__ __bf16 ASh[32][72];
    __shared__ __bf16 BSh[64][72];

    const int tid = threadIdx.x;
    const int lane = tid & 63, w = tid >> 6;
    const int g = lane >> 4, c = lane & 15;
    const int bx = blockIdx.x, by = blockIdx.y;

    int mode, cbase;
    const __bf16* W;
    if (bx < 16)      { mode = 0; W = wqT; cbase = bx * 64; }
    else if (bx < 20) { mode = 1; W = wkT; cbase = (bx - 16) * 64; }
    else              { mode = 2; W = wvT; cbase = (bx - 20) * 64; }

    const int arow = tid >> 3, ak = (tid & 7) * 8;
    const __bf16* Ap = hidb + (size_t)(by * 32 + arow) * EMBED + ak;
    const int bn = tid & 63, bk0 = (tid >> 6) * 16;
    const __bf16* Bp = W + (size_t)(cbase + bn) * 1024 + bk0;

    floatx4 acc[2] = {floatx4(0.f), floatx4(0.f)};

    bf16x8 a0 = *(const bf16x8*)(Ap);
    bf16x8 b0 = *(const bf16x8*)(Bp);
    bf16x8 b1 = *(const bf16x8*)(Bp + 8);

    const int mt = (w & 1) * 16;
    const int nt0 = (w >> 1) * 2;

    for (int k0 = 0; k0 < EMBED; k0 += 64) {
        __syncthreads();
        *(bf16x8*)&ASh[arow][ak] = a0;
        *(bf16x8*)&BSh[bn][bk0] = b0;
        *(bf16x8*)&BSh[bn][bk0 + 8] = b1;
        __syncthreads();
        if (k0 + 64 < EMBED) {
            a0 = *(const bf16x8*)(Ap + k0 + 64);
            b0 = *(const bf16x8*)(Bp + k0 + 64);
            b1 = *(const bf16x8*)(Bp + k0 + 72);
        }
        bf16x8 af0 = *(const bf16x8*)&ASh[mt + c][g * 8];
        bf16x8 af1 = *(const bf16x8*)&ASh[mt + c][32 + g * 8];
#pragma unroll
        for (int t = 0; t < 2; t++) {
            const int tn = nt0 + t;
            bf16x8 bf0 = *(const bf16x8*)&BSh[tn * 16 + c][g * 8];
            bf16x8 bf1 = *(const bf16x8*)&BSh[tn * 16 + c][32 + g * 8];
            acc[t] = __builtin_amdgcn_mfma_f32_16x16x32_bf16(af0, bf0, acc[t], 0, 0, 0);
            acc[t] = __builtin_amdgcn_mfma_f32_16x16x32_bf16(af1, bf1, acc[t], 0, 0, 0);
        }
    }

    const int m0 = mt + g * 4;
    if (mode == 2) {
        const int kvh = bx - 20;
#pragma unroll
        for (int r = 0; r < 4; r++) {
            const int token = by * 32 + m0 + r;
#pragma unroll
            for (int t = 0; t < 2; t++)
                vnp[((size_t)kvh * SN + token) * HD + (nt0 + t) * 16 + c] = acc[t][r];
        }
    } else {
        float fr[2];
#pragma unroll
        for (int t = 0; t < 2; t++) {
            const int d = (cbase + (nt0 + t) * 16 + c) & 63;
            fr[t] = exp2f(-FREQ_C * (float)(d >> 1));
        }
        const int par = c & 1;
#pragma unroll
        for (int r = 0; r < 4; r++) {
            const int token = by * 32 + m0 + r;
            const float ft = (float)new_t[token];
            const float fdb = (float)(new_d[token] + new_b[token]);
#pragma unroll
            for (int t = 0; t < 2; t++) {
                const float ang = ft * fr[t] + fdb * (fr[t] * 100.0f);
                float sv, cv;
                sincosf(ang, &sv, &cv);
                const float x = acc[t][r];
                const float xp = __shfl_xor(x, 1, 64);
                const float y = par ? (xp * sv + x * cv) : (x * cv - xp * sv);
                const int col = cbase + (nt0 + t) * 16 + c;
                if (mode == 0) {
                    qws[(size_t)token * EMBED + col] = (__bf16)y;
                } else {
                    const int kvh = bx - 16;
                    knp[((size_t)kvh * SN + token) * HD + (col & 63)] = y;
                }
            }
        }
    }
}

// ---------------------------------------------------------------------------
// MFMA output projection, 32x64 tiles. grid (16,32).
// ---------------------------------------------------------------------------
__global__ __launch_bounds__(256) void out_mfma_kernel(
    const __bf16* __restrict__ ctxb, const __bf16* __restrict__ woT,
    float* __restrict__ C)
{
    __shared__ __bf16 ASh[32][72];
    __shared__ __bf16 BSh[64][72];

    const int tid = threadIdx.x;
    const int lane = tid & 63, w = tid >> 6;
    const int g = lane >> 4, c = lane & 15;
    const int bx = blockIdx.x, by = blockIdx.y;

    const int arow = tid >> 3, ak = (tid & 7) * 8;
    const __bf16* Ap = ctxb + (size_t)(by * 32 + arow) * EMBED + ak;
    const int bn = tid & 63, bk0 = (tid >> 6) * 16;
    const __bf16* Bp = woT + (size_t)(bx * 64 + bn) * 1024 + bk0;

    floatx4 acc[2] = {floatx4(0.f), floatx4(0.f)};

    bf16x8 a0 = *(const bf16x8*)(Ap);
    bf16x8 b0 = *(const bf16x8*)(Bp);
    bf16x8 b1 = *(const bf16x8*)(Bp + 8);

    const int mt = (w & 1) * 16;
    const int nt0 = (w >> 1) * 2;

    for (int k0 = 0; k0 < EMBED; k0 += 64) {
        __syncthreads();
        *(bf16x8*)&ASh[arow][ak] = a0;
        *(bf16x8*)&BSh[bn][bk0] = b0;
        *(bf16x8*)&BSh[bn][bk0 + 8] = b1;
        __syncthreads();
        if (k0 + 64 < EMBED) {
            a0 = *(const bf16x8*)(Ap + k0 + 64);
            b0 = *(const bf16x8*)(Bp + k0 + 64);
            b1 = *(const bf16x8*)(Bp + k0 + 72);
        }
        bf16x8 af0 = *(const bf16x8*)&ASh[mt + c][g * 8];
        bf16x8 af1 = *(const bf16x8*)&ASh[mt + c][32 + g * 8];
#pragma unroll
        for (int t = 0; t < 2; t++) {
            const int tn = nt0 + t;
            bf16x8 bf0 = *(const bf16x8*)&BSh[tn * 16 + c][g * 8];
            bf16x8 bf1 = *(const bf16x8*)&BSh[tn * 16 + c][32 + g * 8];
            acc[t] = __builtin_amdgcn_mfma_f32_16x16x32_bf16(af0, bf0, acc[t], 0, 0, 0);
            acc[t] = __builtin_amdgcn_mfma_f32_16x16x32_bf16(af1, bf1, acc[t], 0, 0, 0);
        }
    }

    const int m0 = mt + g * 4;
#pragma unroll
    for (int r = 0; r < 4; r++) {
        const int row = by * 32 + m0 + r;
#pragma unroll
        for (int t = 0; t < 2; t++)
            C[(size_t)row * EMBED + bx * 64 + (nt0 + t) * 16 + c] = acc[t][r];
    }
}

// ---------------------------------------------------------------------------
// MFMA flash attention, GQA-fused: one block per (frame, kv-head, split),
// wave w = head kvh*4+w consumes the SHARED K/V staged once per block.
// Fixed-shift softmax; l via ones-MFMA; per-wave-private PS slab; register
// prefetch. grid 512 = 16 f x 4 kvh x 8 split, 256 threads = 4 waves.
// ---------------------------------------------------------------------------
#define PREFETCH_CHUNK(CI)                                                     \
    {                                                                          \
        const int base_ = (myStart + (CI)) << 6;                               \
        const int gk_ = base_ + skk;                                           \
        if (gk_ < Nk) {                                                        \
            const float* kp_ = (gk_ < nPast)                                   \
                ? past_k + ((size_t)(kvh * LP + p0 + gk_)) * HD + sd0          \
                : knp + ((size_t)(kvh * SN + (gk_ - nPast))) * HD + sd0;       \
            kb0 = *(const float4*)(kp_ + 0);                                   \
            kb1 = *(const float4*)(kp_ + 4);                                   \
            kb2 = *(const float4*)(kp_ + 8);                                   \
            kb3 = *(const float4*)(kp_ + 12);                                  \
        } else {                                                               \
            kb0 = kb1 = kb2 = kb3 = make_float4(0.f, 0.f, 0.f, 0.f);           \
        }                                                                      \
        const int gv0_ = base_ + 2 * kp2;                                      \
        if (gv0_ < Nk) {                                                       \
            const float* vp_ = (gv0_ < nPast)                                  \
                ? past_v + ((size_t)(kvh * LP + p0 + gv0_)) * HD + vdb         \
                : vnp + ((size_t)(kvh * SN + (gv0_ - nPast))) * HD + vdb;      \
            vb00 = *(const float4*)(vp_ + 0);                                  \
            vb01 = *(const float4*)(vp_ + 4);                                  \
        } else {                                                               \
            vb00 = vb01 = make_float4(0.f, 0.f, 0.f, 0.f);                     \
        }                                                                      \
        const int gv1_ = gv0_ + 1;                                             \
        if (gv1_ < Nk) {                                                       \
            const float* vp_ = (gv1_ < nPast)                                  \
                ? past_v + ((size_t)(kvh * LP + p0 + gv1_)) * HD + vdb         \
                : vnp + ((size_t)(kvh * SN + (gv1_ - nPast))) * HD + vdb;      \
            vb10 = *(const float4*)(vp_ + 0);                                  \
            vb11 = *(const float4*)(vp_ + 4);                                  \
        } else {                                                               \
            vb10 = vb11 = make_float4(0.f, 0.f, 0.f, 0.f);                     \
        }                                                                      \
        if (tid < 64) {                                                        \
            const int g2_ = base_ + tid;                                       \
            ptreg = (g2_ < Nk)                                                 \
                ? ((g2_ < nPast) ? past_t[p0 + g2_] : new_t[g2_ - nPast])      \
                : 0x7fffffff;                                                  \
        }                                                                      \
    }

__global__ __launch_bounds__(256) void attn_kernel(
    const __bf16* __restrict__ qws, const float* __restrict__ past_k,
    const float* __restrict__ past_v, const float* __restrict__ knp,
    const float* __restrict__ vnp, const int* __restrict__ new_t,
    const int* __restrict__ past_t, float* __restrict__ opart,
    float* __restrict__ lpart)
{
    __shared__ __bf16 KS[64][72];      // K  [key][d] (shared by 4 heads)
    __shared__ __bf16 VS[64][72];      // V^T [d][key]
    __shared__ __bf16 PS[4][64][72];   // per-wave P [q][key]
    __shared__ float MSK[64];

    const int tid = threadIdx.x;
    const int i = blockIdx.x;
    const int kvh = i & 3;
    const int sidx = (i >> 2) & 7;
    const int f = i >> 5;

    const int lane = tid & 63, w = tid >> 6;
    const int g = lane >> 4, c = lane & 15;
    const int h = kvh * 4 + w;   // wave w owns head h

    const int tmax = new_t[SN - 1];
    const int min_time = tmax - (WIN - 1);
    const int qtf = new_t[f * 64];

    int lo = 0, hi = LP;
    while (lo < hi) {
        int mid = (lo + hi) >> 1;
        if (past_t[mid] >= min_time) hi = mid; else lo = mid + 1;
    }
    const int p0 = lo;
    const int nPast = LP - p0;
    const int Nk = nPast + (f + 1) * 64;

    const int nch = (Nk + 63) >> 6;
    const int qch = nch >> 3, rem = nch & 7;
    const int myCount = qch + (sidx < rem ? 1 : 0);
    const int myStart = sidx * qch + (sidx < rem ? sidx : rem);

    // ---- Q fragments: 4 q-tiles x 2 K-steps for head h ----
    bf16x8 aQ[4][2];
#pragma unroll
    for (int qt = 0; qt < 4; qt++) {
        const __bf16* qp = qws + (size_t)(f * 64 + qt * 16 + c) * EMBED + h * HD + g * 8;
        aQ[qt][0] = *(const bf16x8*)(qp);
        aQ[qt][1] = *(const bf16x8*)(qp + 32);
    }

    floatx4 oacc[4][4];
#pragma unroll
    for (int qt = 0; qt < 4; qt++)
#pragma unroll
        for (int t = 0; t < 4; t++) oacc[qt][t] = floatx4(0.f);
    floatx4 lacc[4] = {floatx4(0.f), floatx4(0.f), floatx4(0.f), floatx4(0.f)};
    bf16x8 bOnes;
#pragma unroll
    for (int j = 0; j < 8; j++) bOnes[j] = (__bf16)1.0f;

    const float scale = 0.125f;

    const int skk = tid >> 2, sd0 = (tid & 3) * 16;   // K: key, d-block
    const int kp2 = tid & 31, vdb = (tid >> 5) * 8;   // V: key-pair, d-block

    float4 kb0, kb1, kb2, kb3;
    float4 vb00, vb01, vb10, vb11;
    int ptreg = 0x7fffffff;

    if (myCount > 0) PREFETCH_CHUNK(0);

    for (int chi = 0; chi < myCount; ++chi) {
        __syncthreads();   // prior chunk's KS/VS reads complete

        {
            bf16x8 t0, t1;
            t0[0] = (__bf16)kb0.x; t0[1] = (__bf16)kb0.y;
            t0[2] = (__bf16)kb0.z; t0[3] = (__bf16)kb0.w;
            t0[4] = (__bf16)kb1.x; t0[5] = (__bf16)kb1.y;
            t0[6] = (__bf16)kb1.z; t0[7] = (__bf16)kb1.w;
            t1[0] = (__bf16)kb2.x; t1[1] = (__bf16)kb2.y;
            t1[2] = (__bf16)kb2.z; t1[3] = (__bf16)kb2.w;
            t1[4] = (__bf16)kb3.x; t1[5] = (__bf16)kb3.y;
            t1[6] = (__bf16)kb3.z; t1[7] = (__bf16)kb3.w;
            *(bf16x8*)&KS[skk][sd0] = t0;
            *(bf16x8*)&KS[skk][sd0 + 8] = t1;
        }
        {
            float e0[8] = {vb00.x, vb00.y, vb00.z, vb00.w,
                           vb01.x, vb01.y, vb01.z, vb01.w};
            float e1[8] = {vb10.x, vb10.y, vb10.z, vb10.w,
                           vb11.x, vb11.y, vb11.z, vb11.w};
#pragma unroll
            for (int j = 0; j < 8; j++) {
                union { __bf16 b[2]; unsigned u; } pk;
                pk.b[0] = (__bf16)e0[j];
                pk.b[1] = (__bf16)e1[j];
                *(unsigned*)&VS[vdb + j][2 * kp2] = pk.u;
            }
        }
        if (tid < 64) {
            const int g2 = ((myStart + chi) << 6) + tid;
            const bool ok = (ptreg <= qtf) && ((g2 >= nPast) || (ptreg >= min_time));
            MSK[tid] = ok ? 0.f : -1e30f;
        }
        __syncthreads();

        if (chi + 1 < myCount) PREFETCH_CHUNK(chi + 1);

        // ---- K fragments loaded once, reused by all 4 q-tiles ----
        bf16x8 kf[4][2];
#pragma unroll
        for (int kt = 0; kt < 4; kt++) {
            kf[kt][0] = *(const bf16x8*)&KS[kt * 16 + c][g * 8];
            kf[kt][1] = *(const bf16x8*)&KS[kt * 16 + c][32 + g * 8];
        }
        float mk[4];
#pragma unroll
        for (int kt = 0; kt < 4; kt++) mk[kt] = MSK[kt * 16 + c];

        // ---- per q-tile: S = Q K^T, exp, P -> private PS slab ----
#pragma unroll
        for (int qt = 0; qt < 4; qt++) {
            floatx4 sacc[4];
#pragma unroll
            for (int kt = 0; kt < 4; kt++) {
                sacc[kt] = floatx4(0.f);
                sacc[kt] = __builtin_amdgcn_mfma_f32_16x16x32_bf16(aQ[qt][0], kf[kt][0], sacc[kt], 0, 0, 0);
                sacc[kt] = __builtin_amdgcn_mfma_f32_16x16x32_bf16(aQ[qt][1], kf[kt][1], sacc[kt], 0, 0, 0);
            }
#pragma unroll
            for (int r = 0; r < 4; r++)
#pragma unroll
                for (int kt = 0; kt < 4; kt++)
                    PS[w][qt * 16 + g * 4 + r][kt * 16 + c] =
                        (__bf16)__expf(sacc[kt][r] * scale + mk[kt]);
        }

        // ---- O += P V ; l += P 1 (per wave, own PS slab) ----
#pragma unroll
        for (int s = 0; s < 2; s++) {
            bf16x8 af[4];
#pragma unroll
            for (int qt = 0; qt < 4; qt++)
                af[qt] = *(const bf16x8*)&PS[w][qt * 16 + c][s * 32 + g * 8];
#pragma unroll
            for (int qt = 0; qt < 4; qt++)
                lacc[qt] = __builtin_amdgcn_mfma_f32_16x16x32_bf16(af[qt], bOnes, lacc[qt], 0, 0, 0);
#pragma unroll
            for (int t = 0; t < 4; t++) {
                bf16x8 vf = *(const bf16x8*)&VS[t * 16 + c][s * 32 + g * 8];
#pragma unroll
                for (int qt = 0; qt < 4; qt++)
                    oacc[qt][t] = __builtin_amdgcn_mfma_f32_16x16x32_bf16(af[qt], vf, oacc[qt][t], 0, 0, 0);
            }
        }
    }

    // ---- partial epilogue: raw O and l for head h ----
    float* Op = opart + ((size_t)(f * 16 + h) * 8 + sidx) * 4096;
    float* lp = lpart + ((size_t)(f * 16 + h) * 8 + sidx) * 64;
#pragma unroll
    for (int qt = 0; qt < 4; qt++) {
#pragma unroll
        for (int r = 0; r < 4; r++) {
            const int q = qt * 16 + g * 4 + r;
#pragma unroll
            for (int t = 0; t < 4; t++)
                Op[(size_t)q * 64 + t * 16 + c] = oacc[qt][t][r];
            if (c == 0) lp[q] = lacc[qt][r];
        }
    }
}

// ---------------------------------------------------------------------------
// Merge 8 split-K partials -> bf16 ctx. grid (16,16), 256 threads.
// ---------------------------------------------------------------------------
__global__ __launch_bounds__(256) void attn_merge_kernel(
    const float* __restrict__ opart, const float* __restrict__ lpart,
    __bf16* __restrict__ ctxb)
{
    const int f = blockIdx.x, h = blockIdx.y;
    const int tid = threadIdx.x;
    const int q = tid >> 2, d0 = (tid & 3) * 16;
    const size_t fh = (size_t)(f * 16 + h);

    float l = 0.f;
#pragma unroll
    for (int s = 0; s < 8; s++) l += lpart[(fh * 8 + s) * 64 + q];
    const float inv = (l > 0.f) ? (1.f / l) : 0.f;

    float o[16] = {};
#pragma unroll
    for (int s = 0; s < 8; s++) {
        const float* Os = opart + (fh * 8 + s) * 4096 + (size_t)q * 64 + d0;
#pragma unroll
        for (int v = 0; v < 4; v++) {
            float4 ov = *(const float4*)(Os + v * 4);
            o[v * 4 + 0] += ov.x;
            o[v * 4 + 1] += ov.y;
            o[v * 4 + 2] += ov.z;
            o[v * 4 + 3] += ov.w;
        }
    }
    bf16x8 o0, o1;
#pragma unroll
    for (int j = 0; j < 8; j++) {
        o0[j] = (__bf16)(o[j] * inv);
        o1[j] = (__bf16)(o[8 + j] * inv);
    }
    __bf16* cp = ctxb + (size_t)(f * 64 + q) * EMBED + h * HD + d0;
    *(bf16x8*)cp = o0;
    *(bf16x8*)(cp + 8) = o1;
}

// ---------------------------------------------------------------------------
extern "C" void kernel_launch(void* const* d_in, const int* in_sizes, int n_in,
                              void* d_out, int out_size, void* d_ws, size_t ws_size,
                              hipStream_t stream) {
    const float* hidden = (const float*)d_in[0];
    const float* past_k = (const float*)d_in[1];
    const float* past_v = (const float*)d_in[2];
    const float* wq     = (const float*)d_in[3];
    const float* wk     = (const float*)d_in[4];
    const float* wv     = (const float*)d_in[5];
    const float* wo     = (const float*)d_in[6];
    const int* new_t    = (const int*)d_in[7];
    const int* new_d    = (const int*)d_in[8];
    const int* new_b    = (const int*)d_in[9];
    const int* past_t   = (const int*)d_in[10];

    float* out = (float*)d_out;                 // (1,1024,1024)
    float* knp = out + SN * EMBED;              // (1,4,1024,64) roped Kn
    float* vnp = knp + NKV * SN * HD;           // (1,4,1024,64) Vn

    // workspace layout:
    float* lpart = (float*)d_ws;                         // 16*16*8*64 floats
    float* opart = lpart + (size_t)16 * 16 * 8 * 64;     // 16*16*8*4096 floats
    __bf16* qws  = (__bf16*)(opart + (size_t)16 * 16 * 8 * 4096);  // 1M bf16
    __bf16* hidb = qws + (size_t)SN * EMBED;             // 1M bf16
    __bf16* wqT  = hidb + (size_t)SN * EMBED;            // 1M bf16
    __bf16* wkT  = wqT + (size_t)1024 * 1024;            // 256K bf16
    __bf16* wvT  = wkT + (size_t)256 * 1024;             // 256K bf16
    __bf16* woT  = wvT + (size_t)256 * 1024;             // 1M bf16
    __bf16* ctxb = woT + (size_t)1024 * 1024;            // 1M bf16

    prep_kernel<<<dim3(896), 256, 0, stream>>>(
        hidden, wq, wk, wv, wo, hidb, wqT, wkT, wvT, woT);
    qkv_mfma_kernel<<<dim3(24, 32), 256, 0, stream>>>(
        hidb, wqT, wkT, wvT, new_t, new_d, new_b, qws, knp, vnp);
    attn_kernel<<<dim3(512), 256, 0, stream>>>(
        qws, past_k, past_v, knp, vnp, new_t, past_t, opart, lpart);
    attn_merge_kernel<<<dim3(16, 16), 256, 0, stream>>>(opart, lpart, ctxb);
    out_mfma_kernel<<<dim3(16, 32), 256, 0, stream>>>(ctxb, woT, out);
}